// Round 7
// baseline (154.246 us; speedup 1.0000x reference)
//
#include <hip/hip_runtime.h>
#include <cstdint>
#include <cstddef>

#define BB  2
#define TT  2048
#define CC  1024
#define NHH 16
#define HSS 64
#define BT  (BB*TT)   // 4096

#define LOG2E 1.44269504088896f
#define S0INIT (-28.8539008f)   // -20 * log2(e)

typedef unsigned short u16;
typedef unsigned int u32;
typedef __attribute__((ext_vector_type(2))) unsigned int u32x2;
typedef _Float16 f16;
typedef __attribute__((ext_vector_type(8))) _Float16 f16x8;
typedef __attribute__((ext_vector_type(8))) __bf16 bf16x8;
typedef __attribute__((ext_vector_type(4))) float f32x4;

__device__ __forceinline__ u16 f2bf(float f) {
    union { float f; u32 u; } x; x.f = f;
    return (u16)((x.u + 0x7fffu + ((x.u >> 16) & 1u)) >> 16);
}
__device__ __forceinline__ u16 f2h(float f) {
    union { f16 h; u16 u; } x; x.h = (f16)f;
    return x.u;
}
// packed f32 pair -> bf16x2 in one u32 (RNE), single VALU op
__device__ __forceinline__ u32 cvtpk_bf16(float lo, float hi) {
    u32 r;
    asm("v_cvt_pk_bf16_f32 %0, %1, %2" : "=v"(r) : "v"(lo), "v"(hi));
    return r;
}

#define MFMA_BF(a,b,c) __builtin_amdgcn_mfma_f32_16x16x32_bf16((a),(b),(c),0,0,0)
#define MFMA_F16(a,b,c) __builtin_amdgcn_mfma_f32_16x16x32_f16((a),(b),(c),0,0,0)

// async global->LDS, 16B/lane; LDS dest = wave-uniform base + lane*16
__device__ __forceinline__ void gld16(const u16* g, u16* l) {
    __builtin_amdgcn_global_load_lds(
        (const __attribute__((address_space(1))) unsigned int*)g,
        (__attribute__((address_space(3))) unsigned int*)l, 16, 0, 0);
}

// ---------------------------------------------------------------------------
// convert_xw: merged converter (one launch instead of two).
// bid < 2048: x fp32 -> Xf fp16 (coalesced float4 x2 -> uint4).
// bid >= 2048: W [k][n] fp32 -> WT [n][k] fp16 via LDS transpose.
// ---------------------------------------------------------------------------
__global__ __launch_bounds__(256) void convert_xw(
    const float* __restrict__ X, const float* __restrict__ Wk,
    const float* __restrict__ Wv, u16* __restrict__ Xf,
    u16* __restrict__ WkT, u16* __restrict__ WvT)
{
    __shared__ __align__(16) u16 LH[64][72];
    const int bid = blockIdx.x;
    const int tid = threadIdx.x;
    if (bid < 2048) {
        const int idx = (bid * 256 + tid) * 8;
        const float4 a = *(const float4*)&X[idx];
        const float4 b = *(const float4*)&X[idx + 4];
        float v[8] = {a.x, a.y, a.z, a.w, b.x, b.y, b.z, b.w};
        union { uint4 u; u16 s[8]; } H;
        #pragma unroll
        for (int u = 0; u < 8; ++u) H.s[u] = f2h(v[u]);
        *(uint4*)&Xf[idx] = H.u;
        return;
    }
    const int bid2 = bid - 2048;          // [0,512)
    const bool isK = (bid2 >> 8) == 0;
    const int rem = bid2 & 255;
    const int n0 = (rem & 15) * 64, k0 = (rem >> 4) * 64;
    const float* W = isK ? Wk : Wv;
    u16* WT = isK ? WkT : WvT;
    {
        const int row = tid >> 2, coff = (tid & 3) * 16;
        const float* g = &W[(size_t)(k0 + row) * CC + n0 + coff];
        #pragma unroll
        for (int u = 0; u < 16; ++u) LH[row][coff + u] = f2h(g[u]);
    }
    __syncthreads();
    {
        const int n = tid >> 2, kc = (tid & 3) * 16;
        union { uint4 u[2]; u16 s[16]; } Hq;
        #pragma unroll
        for (int u = 0; u < 16; ++u) Hq.s[u] = LH[kc + u][n];
        uint4* ph = (uint4*)&WT[(size_t)(n0 + n) * CC + k0 + kc];
        ph[0] = Hq.u[0]; ph[1] = Hq.u[1];
    }
}

// ---------------------------------------------------------------------------
// proj_kernel: 128x128 fp16 GEMM, BK=32, FOUR-buffer gld16 staging staged
// TWO tiles ahead with counted vmcnt (certify-then-barrier: stage ->
// vmcnt(8) -> s_barrier; never vmcnt(0) in-loop). Barrier is the BUILTIN
// __builtin_amdgcn_s_barrier (m201-verified pattern; raw asm s_barrier was
// the R6 hang suspect). One barrier per k-iter; loads get ~2 iterations of
// latency slack. LDS 64 KB -> 2 blocks/CU. z mapped to XCD halves (K-proj
// on XCD 0-3, V on 4-7) so per-XCD staging working set fits 4MB L2.
// Race analysis: stage(ki+2) writes buf (ki+2)&3 whose last readers ran at
// iter ki-2, two collective barriers back; every wave certifies its OWN
// tile-ki loads via vmcnt BEFORE the barrier, so after the barrier the
// buffer is globally complete.
// z=0: Kproj -> Kf fp16 [t][c], PRE-SCALED by log2(e).
// z=1: V -> Vt bf16 head-transposed [b][h][d][T].
// ---------------------------------------------------------------------------
__global__ __launch_bounds__(256) void proj_kernel(
    const u16* __restrict__ Xf, const u16* __restrict__ WkT,
    const u16* __restrict__ WvT,
    const float* __restrict__ bk, const float* __restrict__ bv,
    u16* __restrict__ Kf, u16* __restrict__ Vt)
{
    __shared__ __align__(16) u16 SM[4][8192];  // 4 bufs x (A 8KB + B 8KB) = 64KB

    const int id = blockIdx.x;
    const int xcd = id & 7;                    // hw XCD (round-robin dispatch)
    const int z = xcd >> 2, xcd4 = xcd & 3;    // z pinned to an XCD half
    const int idx = id >> 3;                   // [0,64)
    const int n0 = (idx & 7) * 128;
    const int m0 = (xcd4 * 8 + (idx >> 3)) * 128;
    const bool isK = (z == 0);
    const u16* WT = isK ? WkT : WvT;

    const int tid = threadIdx.x;
    const int w = tid >> 6, lane = tid & 63;
    const int quad = lane >> 4, l15 = lane & 15;
    const int wm = (w >> 1) * 64, wn = (w & 1) * 64;

    // staging: waves 0,1 -> A (Xf rows m0..), waves 2,3 -> B (WT rows n0..)
    const u16* src = (w < 2) ? Xf : WT;
    const int rbase = (w < 2) ? m0 : n0;
    int srow[4], scg[4];
    #pragma unroll
    for (int t = 0; t < 4; ++t) {
        const int ci = (w & 1) * 256 + t * 64 + lane;   // [0,512) chunk id
        const int r = ci >> 2;                          // row [0,128)
        srow[t] = r;
        scg[t] = ((ci & 3) - r - (r >> 2)) & 3;         // mod-4 swizzle +r>>2
    }
    const int dhalf = ((w >= 2) ? 4096 : 0) + (w & 1) * 2048;  // u16 offset
    const u16* gsrc[4];
    #pragma unroll
    for (int t = 0; t < 4; ++t)
        gsrc[t] = src + (size_t)(rbase + srow[t]) * CC + scg[t] * 8;

    // loop-invariant read offsets (bytes within a buf)
    const char* smb = (const char*)&SM[0][0];
    int aoff[4], boff[4];
    #pragma unroll
    for (int i = 0; i < 4; ++i) {
        const int r = wm + i * 16 + l15;
        aoff[i] = r * 64 + ((quad + r + (r >> 2)) & 3) * 16;
    }
    #pragma unroll
    for (int j = 0; j < 4; ++j) {
        const int r = wn + j * 16 + l15;
        boff[j] = 8192 + r * 64 + ((quad + r + (r >> 2)) & 3) * 16;
    }

    f32x4 acc[4][4] = {};

#define PSTAGE(K, BI)                                                   \
    { u16* dst = &SM[BI][dhalf];                                        \
      _Pragma("unroll")                                                 \
      for (int t = 0; t < 4; ++t)                                       \
          gld16(gsrc[t] + (K) * 32, dst + t * 512); }

    PSTAGE(0, 0);
    PSTAGE(1, 1);

    for (int ki = 0; ki < 32; ++ki) {
        const int buf = ki & 3;
        if (ki < 30) PSTAGE(ki + 2, (ki + 2) & 3);
        if (ki < 30)       asm volatile("s_waitcnt vmcnt(8)" ::: "memory");
        else if (ki == 30) asm volatile("s_waitcnt vmcnt(4)" ::: "memory");
        else               asm volatile("s_waitcnt vmcnt(0)" ::: "memory");
        __builtin_amdgcn_sched_barrier(0);
        __builtin_amdgcn_s_barrier();
        __builtin_amdgcn_sched_barrier(0);
        const char* pb = smb + buf * 16384;
        f16x8 ah[4];
        #pragma unroll
        for (int i = 0; i < 4; ++i) ah[i] = *(const f16x8*)(pb + aoff[i]);
        #pragma unroll
        for (int j = 0; j < 4; ++j) {
            f16x8 bh = *(const f16x8*)(pb + boff[j]);
            #pragma unroll
            for (int i = 0; i < 4; ++i)
                acc[i][j] = MFMA_F16(ah[i], bh, acc[i][j]);
        }
    }
#undef PSTAGE

    __syncthreads();               // full drain once; reuse SM for epilogue
    u16* XL = &SM[0][0];           // stride 136 (17408 u16 = 34 KB)

    if (isK) {
        #pragma unroll
        for (int j = 0; j < 4; ++j) {
            const float bias = bk[n0 + wn + j * 16 + l15];
            #pragma unroll
            for (int i = 0; i < 4; ++i)
                #pragma unroll
                for (int r = 0; r < 4; ++r)
                    XL[(wm + i * 16 + quad * 4 + r) * 136 + wn + j * 16 + l15] =
                        f2h((acc[i][j][r] + bias) * LOG2E);
        }
        __syncthreads();
        const int r = tid >> 1, half = tid & 1;
        #pragma unroll
        for (int t = 0; t < 8; ++t)
            *(uint4*)&Kf[(size_t)(m0 + r) * CC + n0 + half * 64 + t * 8] =
                *(const uint4*)&XL[r * 136 + half * 64 + t * 8];
    } else {
        // write transposed [n-local][t-local]: 4 consecutive t -> uint2
        #pragma unroll
        for (int j = 0; j < 4; ++j) {
            const float bias = bv[n0 + wn + j * 16 + l15];
            #pragma unroll
            for (int i = 0; i < 4; ++i) {
                uint2 pk;
                pk.x = (u32)f2bf(acc[i][j][0] + bias) |
                       ((u32)f2bf(acc[i][j][1] + bias) << 16);
                pk.y = (u32)f2bf(acc[i][j][2] + bias) |
                       ((u32)f2bf(acc[i][j][3] + bias) << 16);
                *(uint2*)&XL[(wn + j * 16 + l15) * 136 + wm + i * 16 + quad * 4] = pk;
            }
        }
        __syncthreads();
        const int nl = tid >> 1, half = tid & 1;
        const int d = (n0 + nl) & (HSS - 1), hh = (n0 + nl) >> 6;
        const int bb = m0 >> 11, tb = (m0 & (TT - 1)) + half * 64;
        const size_t gb = ((size_t)(bb * NHH + hh) * HSS + d) * TT + tb;
        #pragma unroll
        for (int t = 0; t < 8; ++t)
            *(uint4*)&Vt[gb + t * 8] = *(const uint4*)&XL[nl * 136 + half * 64 + t * 8];
    }
}

// ---------------------------------------------------------------------------
// attn: paired i-tiles (k, 31-k) -> 512 uniform blocks, XCD swizzle.
// R4-verified body (best attn measured: 48.2us, 88 VGPR), non-split, direct
// fp32 store. gld16 double-buffered X/V staging, one __syncthreads per
// j-tile (its drain is covered by ~2000cyc of compute). fp16 S with bias
// -20*log2e in MFMA C-init; Kf pre-scaled by log2e -> bare exp2f. P fully
// in registers: cvt_pk_bf16 + builtin permlane16_swap; k-groups permuted
// pi={0,2,1,3}, compensated by reading V B-fragments at chunk pi(quad).
// l via ones-MFMA (k-permutation invariant).
// ---------------------------------------------------------------------------
__global__ __launch_bounds__(256) void attn_kernel(
    const u16* __restrict__ Xf, const u16* __restrict__ Kf,
    const u16* __restrict__ Vt, float* __restrict__ out)
{
    __shared__ __align__(16) u16 Xs[2][4096];  // x rows [j][d], chunk-swizzled
    __shared__ __align__(16) u16 Vs[2][4096];  // V^T [d][j], chunk-swizzled

    const int L = blockIdx.x;
    const int xcd = L & 7, k = (L >> 3) & 15, grp = L >> 7;
    const int hb = xcd + 8 * grp;
    const int h = hb & (NHH - 1), b = hb >> 4;
    const int iA = k, iB = 31 - k;
    const int i0A = iA * 64, i0B = iB * 64;

    const int tid = threadIdx.x;
    const int w = tid >> 6, lane = tid & 63;
    const int quad = lane >> 4, l15 = lane & 15;
    const int pq = ((quad & 1) << 1) | (quad >> 1);      // pi(quad)={0,2,1,3}
    const size_t rowbase = (size_t)b * TT;
    const int hd = h * HSS;
    const size_t vgbase = (size_t)(b * NHH + h) * HSS * TT;

    bf16x8 ones;
    { union { u32 u[4]; bf16x8 v; } o;
      #pragma unroll
      for (int i = 0; i < 4; ++i) o.u[i] = 0x3F803F80u;
      ones = o.v; }

    // hoist Q (projected-K, log2e-scaled) B-fragments for both tiles
    f16x8 qA[2], qB[2];
    #pragma unroll
    for (int c = 0; c < 2; ++c) {
        qA[c] = *(const f16x8*)&Kf[(rowbase + i0A + w * 16 + l15) * CC + hd + c * 32 + quad * 8];
        qB[c] = *(const f16x8*)&Kf[(rowbase + i0B + w * 16 + l15) * CC + hd + c * 32 + quad * 8];
    }

    // gld16 staging descriptors: 2 chunks per lane per array
    int crow[2], ccg[2], cbase[2];
    #pragma unroll
    for (int t = 0; t < 2; ++t) {
        const int ci = t * 256 + tid;
        crow[t] = ci >> 3;
        ccg[t] = ((ci & 7) - crow[t]) & 7;
        cbase[t] = (t * 256 + w * 64) * 8;
    }
    const u16* gx[2]; const u16* gv[2];
    #pragma unroll
    for (int t = 0; t < 2; ++t) {
        gx[t] = Xf + (rowbase + crow[t]) * CC + hd + ccg[t] * 8;
        gv[t] = Vt + vgbase + (size_t)crow[t] * TT + ccg[t] * 8;
    }

    // prologue: stage tile jt=0 into buf 0
    #pragma unroll
    for (int t = 0; t < 2; ++t) {
        gld16(gx[t], Xs[0] + cbase[t]);
        gld16(gv[t], Vs[0] + cbase[t]);
    }

    f32x4 oA[4] = {}, oB[4] = {};
    f32x4 laA = {}, laB = {};

    for (int jt = 0; jt <= iB; ++jt) {
        const int buf = jt & 1;
        __syncthreads();          // buf ready (vmcnt drained); prev reads done
        if (jt < iB) {
            const int j0n = (jt + 1) * 64;
            #pragma unroll
            for (int t = 0; t < 2; ++t) {
                gld16(gx[t] + (size_t)j0n * CC, Xs[buf ^ 1] + cbase[t]);
                gld16(gv[t] + j0n, Vs[buf ^ 1] + cbase[t]);
            }
        }
        const bool doA = (jt <= iA);

        // ---- S for both tiles, sharing xb fragments; SWAPPED operands:
        // lane (quad,l15) reg r holds S[i = w*16+l15][j = nt*16+quad*4+r]
        f32x4 sB[4], sA[4];
        #pragma unroll
        for (int nt = 0; nt < 4; ++nt) {
            const int krow = nt * 16 + l15;
            f16x8 x0 = *(const f16x8*)&Xs[buf][krow * 64 + ((quad + krow) & 7) * 8];
            f16x8 x1 = *(const f16x8*)&Xs[buf][krow * 64 + ((quad + 4 + krow) & 7) * 8];
            f32x4 z = {S0INIT, S0INIT, S0INIT, S0INIT};
            z = MFMA_F16(x0, qB[0], z);
            z = MFMA_F16(x1, qB[1], z);
            sB[nt] = z;
            if (doA) {
                f32x4 y = {S0INIT, S0INIT, S0INIT, S0INIT};
                y = MFMA_F16(x0, qA[0], y);
                y = MFMA_F16(x1, qA[1], y);
                sA[nt] = y;
            }
        }
        if (jt == iB) {
            #pragma unroll
            for (int nt = 0; nt < 4; ++nt)
                #pragma unroll
                for (int r = 0; r < 4; ++r)
                    if (nt * 16 + quad * 4 + r > w * 16 + l15) sB[nt][r] = -1e30f;
        }
        if (doA && jt == iA) {
            #pragma unroll
            for (int nt = 0; nt < 4; ++nt)
                #pragma unroll
                for (int r = 0; r < 4; ++r)
                    if (nt * 16 + quad * 4 + r > w * 16 + l15) sA[nt][r] = -1e30f;
        }

        // ---- exp2 + in-register pack + permlane16_swap quad-redistribution
        u32 pB_[4][2];
        #pragma unroll
        for (int nt = 0; nt < 4; ++nt) {
            pB_[nt][0] = cvtpk_bf16(exp2f(sB[nt][0]), exp2f(sB[nt][1]));
            pB_[nt][1] = cvtpk_bf16(exp2f(sB[nt][2]), exp2f(sB[nt][3]));
        }
        #pragma unroll
        for (int c = 0; c < 2; ++c)
            #pragma unroll
            for (int p = 0; p < 2; ++p) {
                u32x2 sw = __builtin_amdgcn_permlane16_swap(
                    pB_[2 * c][p], pB_[2 * c + 1][p], false, false);
                pB_[2 * c][p] = sw[0];
                pB_[2 * c + 1][p] = sw[1];
            }
        union { u32 u[4]; bf16x8 v; } ub0, ub1;
        ub0.u[0] = pB_[0][0]; ub0.u[1] = pB_[0][1];
        ub0.u[2] = pB_[1][0]; ub0.u[3] = pB_[1][1];
        ub1.u[0] = pB_[2][0]; ub1.u[1] = pB_[2][1];
        ub1.u[2] = pB_[3][0]; ub1.u[3] = pB_[3][1];
        bf16x8 aB0 = ub0.v, aB1 = ub1.v;

        bf16x8 aA0, aA1;
        if (doA) {
            u32 pA_[4][2];
            #pragma unroll
            for (int nt = 0; nt < 4; ++nt) {
                pA_[nt][0] = cvtpk_bf16(exp2f(sA[nt][0]), exp2f(sA[nt][1]));
                pA_[nt][1] = cvtpk_bf16(exp2f(sA[nt][2]), exp2f(sA[nt][3]));
            }
            #pragma unroll
            for (int c = 0; c < 2; ++c)
                #pragma unroll
                for (int p = 0; p < 2; ++p) {
                    u32x2 sw = __builtin_amdgcn_permlane16_swap(
                        pA_[2 * c][p], pA_[2 * c + 1][p], false, false);
                    pA_[2 * c][p] = sw[0];
                    pA_[2 * c + 1][p] = sw[1];
                }
            union { u32 u[4]; bf16x8 v; } ua0, ua1;
            ua0.u[0] = pA_[0][0]; ua0.u[1] = pA_[0][1];
            ua0.u[2] = pA_[1][0]; ua0.u[3] = pA_[1][1];
            ua1.u[0] = pA_[2][0]; ua1.u[1] = pA_[2][1];
            ua1.u[2] = pA_[3][0]; ua1.u[3] = pA_[3][1];
            aA0 = ua0.v; aA1 = ua1.v;
        }

        // ---- l via ones-MFMA (k-permutation invariant) ----
        laB = MFMA_BF(aB0, ones, laB);
        laB = MFMA_BF(aB1, ones, laB);
        if (doA) {
            laA = MFMA_BF(aA0, ones, laA);
            laA = MFMA_BF(aA1, ones, laA);
        }

        // ---- PV, sharing bv fragments; V read at logical chunk pi(quad) ----
        #pragma unroll
        for (int dt = 0; dt < 4; ++dt) {
            const int vrow = dt * 16 + l15;
            bf16x8 v0 = *(const bf16x8*)&Vs[buf][vrow * 64 + ((pq + vrow) & 7) * 8];
            bf16x8 v1 = *(const bf16x8*)&Vs[buf][vrow * 64 + ((pq + 4 + vrow) & 7) * 8];
            oB[dt] = MFMA_BF(aB0, v0, oB[dt]);
            oB[dt] = MFMA_BF(aB1, v1, oB[dt]);
            if (doA) {
                oA[dt] = MFMA_BF(aA0, v0, oA[dt]);
                oA[dt] = MFMA_BF(aA1, v1, oA[dt]);
            }
        }
    }

    // ---- epilogue: normalize, fp32 store, both tiles ----
    float liA[4], liB[4];
    #pragma unroll
    for (int r = 0; r < 4; ++r) { liA[r] = 1.f / laA[r]; liB[r] = 1.f / laB[r]; }
    #pragma unroll
    for (int dt = 0; dt < 4; ++dt) {
        #pragma unroll
        for (int r = 0; r < 4; ++r) {
            const int igA = i0A + w * 16 + quad * 4 + r;
            const int igB = i0B + w * 16 + quad * 4 + r;
            out[(rowbase + igA) * CC + hd + dt * 16 + l15] = oA[dt][r] * liA[r];
            out[(rowbase + igB) * CC + hd + dt * 16 + l15] = oB[dt][r] * liB[r];
        }
    }
}

extern "C" void kernel_launch(void* const* d_in, const int* in_sizes, int n_in,
                              void* d_out, int out_size, void* d_ws, size_t ws_size,
                              hipStream_t stream) {
    (void)in_sizes; (void)n_in; (void)out_size; (void)ws_size;
    const float* x  = (const float*)d_in[0];
    const float* Wk = (const float*)d_in[1];
    const float* bk = (const float*)d_in[2];
    const float* Wv = (const float*)d_in[3];
    const float* bv = (const float*)d_in[4];
    float* out = (float*)d_out;

    const size_t M4 = (size_t)BT * CC;   // 4M elements
    const size_t M1 = (size_t)CC * CC;   // 1M elements
    u16* Xf  = (u16*)d_ws;               // fp16, 8 MB
    u16* Kf  = Xf + M4;                  // fp16 (log2e-scaled), 8 MB
    u16* Vt  = Kf + M4;                  // bf16, 8 MB
    u16* WkT = Vt + M4;                  // fp16, 2 MB
    u16* WvT = WkT + M1;                 // fp16, 2 MB  (28 MB total)

    convert_xw<<<dim3(2560), 256, 0, stream>>>(x, Wk, Wv, Xf, WkT, WvT);
    proj_kernel<<<dim3(512), 256, 0, stream>>>(Xf, WkT, WvT, bk, bv, Kf, Vt);
    attn_kernel<<<dim3(512), 256, 0, stream>>>(Xf, Kf, Vt, out);
}